// Round 1
// baseline (807.238 us; speedup 1.0000x reference)
//
#include <hip/hip_runtime.h>
#include <hip/hip_bf16.h>
#include <math.h>

// Problem: UniMP 2-layer TransformerConv GNN. N=50000, E=800000, G=512, all dims 64 (edge 16).
// Strategy: build CSR by dst once per call; one wave per node does one-pass online-softmax
// aggregation (no atomics in hot path). Fused linear kernels with LDS-resident weights.

#define DH 64

// ---------------- CSR build ----------------

__global__ void hist_kernel(const int* __restrict__ dst, int* __restrict__ deg, int E) {
    int e = blockIdx.x * blockDim.x + threadIdx.x;
    if (e < E) atomicAdd(&deg[dst[e]], 1);
}

__global__ void scan1_kernel(const int* __restrict__ deg, int* __restrict__ row_ptr,
                             int* __restrict__ totals, int N) {
    __shared__ int sh[1024];
    int tid = threadIdx.x;
    int i = blockIdx.x * 1024 + tid;
    int d = (i < N) ? deg[i] : 0;
    int val = d;
    sh[tid] = val;
    __syncthreads();
    for (int off = 1; off < 1024; off <<= 1) {
        int add = (tid >= off) ? sh[tid - off] : 0;
        __syncthreads();
        val += add;
        sh[tid] = val;
        __syncthreads();
    }
    if (i < N) row_ptr[i] = val - d;       // exclusive within chunk
    if (tid == 1023) totals[blockIdx.x] = val;
}

__global__ void scan2_kernel(int* totals, int nb) {
    if (threadIdx.x == 0 && blockIdx.x == 0) {
        int run = 0;
        for (int b = 0; b < nb; ++b) { int t = totals[b]; totals[b] = run; run += t; }
    }
}

__global__ void scan3_kernel(int* __restrict__ row_ptr, const int* __restrict__ totals,
                             int N, int E) {
    int i = blockIdx.x * blockDim.x + threadIdx.x;
    if (i < N) row_ptr[i] += totals[i >> 10];
    if (i == 0) row_ptr[N] = E;
}

__global__ void scatter_kernel(const int* __restrict__ src, const int* __restrict__ dst,
                               const int* __restrict__ row_ptr, int* __restrict__ fill,
                               int* __restrict__ csr_src, int* __restrict__ csr_eid, int E) {
    int e = blockIdx.x * blockDim.x + threadIdx.x;
    if (e < E) {
        int d = dst[e];
        int pos = row_ptr[d] + atomicAdd(&fill[d], 1);
        csr_src[pos] = src[e];
        csr_eid[pos] = e;
    }
}

// ---------------- fused node linears: out = x @ W + b, one matrix per blockIdx.y ----------------
// blockIdx.y: 0->q 1->k 2->v 3->skip. Tile of 64 nodes per blockIdx.x.

#define QK_TN 64

__global__ __launch_bounds__(256) void qkvs_kernel(
    const float* __restrict__ xin,
    const float* __restrict__ wq, const float* __restrict__ bq,
    const float* __restrict__ wk, const float* __restrict__ bk,
    const float* __restrict__ wv, const float* __restrict__ bv,
    const float* __restrict__ ws, const float* __restrict__ bs,
    float* __restrict__ qo, float* __restrict__ ko,
    float* __restrict__ vo, float* __restrict__ so, int N)
{
    int mtx = blockIdx.y;
    const float* wsel = (mtx == 0) ? wq : (mtx == 1) ? wk : (mtx == 2) ? wv : ws;
    const float* bsel = (mtx == 0) ? bq : (mtx == 1) ? bk : (mtx == 2) ? bv : bs;
    float*       outb = (mtx == 0) ? qo : (mtx == 1) ? ko : (mtx == 2) ? vo : so;

    __shared__ float W[64][64];      // W[j][col]
    __shared__ float X[QK_TN][64];   // X[node][j]
    int t = threadIdx.x;
    int col = t & 63;
    int sub = t >> 6;                // 0..3, each handles 16 nodes of the tile

    for (int r = t; r < 64 * 64; r += 256) W[r >> 6][r & 63] = wsel[r];
    int n0 = blockIdx.x * QK_TN;
    for (int r = t; r < QK_TN * 64; r += 256) {
        int n = n0 + (r >> 6);
        X[r >> 6][r & 63] = (n < N) ? xin[(size_t)n * 64 + (r & 63)] : 0.f;
    }
    __syncthreads();

    float bcol = bsel[col];
    for (int nb = sub * 16; nb < sub * 16 + 16; nb += 8) {
        float acc[8];
        #pragma unroll
        for (int u = 0; u < 8; ++u) acc[u] = bcol;
        for (int j = 0; j < 64; ++j) {
            float wjt = W[j][col];
            #pragma unroll
            for (int u = 0; u < 8; ++u) acc[u] = fmaf(X[nb + u][j], wjt, acc[u]);
        }
        #pragma unroll
        for (int u = 0; u < 8; ++u) {
            int n = n0 + nb + u;
            if (n < N) outb[(size_t)n * 64 + col] = acc[u];
        }
    }
}

// ---------------- per-node online-softmax aggregation ----------------
// One wave (64 lanes) per node; lane = feature dim. Single pass over incident edges.
// h_out = leaky( agg + skip ), skip pre-stored in skip_in (may alias hout).

__global__ __launch_bounds__(256) void agg_kernel(
    const float* __restrict__ q, const float* __restrict__ k, const float* __restrict__ v,
    const float* __restrict__ we, const float* __restrict__ edge_attr,
    const int* __restrict__ row_ptr, const int* __restrict__ csr_src,
    const int* __restrict__ csr_eid,
    const float* __restrict__ skip_in, float* __restrict__ hout, int N)
{
    int wid = (blockIdx.x * blockDim.x + threadIdx.x) >> 6;
    int lane = threadIdx.x & 63;
    if (wid >= N) return;
    int i = wid;

    float wer[16];
    #pragma unroll
    for (int j = 0; j < 16; ++j) wer[j] = we[j * 64 + lane];
    float ql = q[(size_t)i * 64 + lane];

    float m = -__builtin_inff(), den = 0.f, o = 0.f;
    int beg = row_ptr[i], end = row_ptr[i + 1];
    for (int p = beg; p < end; ++p) {
        int s = csr_src[p];
        int e = csr_eid[p];
        float kl = k[(size_t)s * 64 + lane];
        float vl = v[(size_t)s * 64 + lane];
        float ea = (lane < 16) ? edge_attr[(size_t)e * 16 + lane] : 0.f;
        float ee = 0.f;
        #pragma unroll
        for (int j = 0; j < 16; ++j) ee = fmaf(__shfl(ea, j, 64), wer[j], ee);
        float sc = ql * (kl + ee);
        #pragma unroll
        for (int off = 32; off > 0; off >>= 1) sc += __shfl_xor(sc, off, 64);
        sc *= 0.125f;                       // / sqrt(64)
        float nm = fmaxf(m, sc);
        float f = __expf(m - nm);           // first iter: exp(-inf)=0
        float w = __expf(sc - nm);
        den = den * f + w;
        o = o * f + w * (vl + ee);
        m = nm;
    }
    float dinv = (den > 0.f) ? 1.f / den : 0.f;   // no edges -> agg = 0 (matches ref)
    float r = o * dinv + skip_in[(size_t)i * 64 + lane];
    hout[(size_t)i * 64 + lane] = (r >= 0.f) ? r : 0.01f * r;
}

// ---------------- pooling + head ----------------

__global__ void pool_kernel(const float* __restrict__ atom, const int* __restrict__ batch,
                            float* __restrict__ pooled, int N) {
    int idx = blockIdx.x * blockDim.x + threadIdx.x;
    if (idx < N * 64) {
        int i = idx >> 6;
        atomicAdd(&pooled[batch[i] * 64 + (idx & 63)], atom[idx]);
    }
}

__global__ void head_kernel(const float* __restrict__ pooled,
                            const float* __restrict__ w1, const float* __restrict__ b1,
                            const float* __restrict__ w2, const float* __restrict__ b2,
                            float* __restrict__ out, int G) {
    int g = blockIdx.x;
    int lane = threadIdx.x;   // 64
    __shared__ float hl[64];
    float p = pooled[g * 64 + lane];
    float ss = p * p;
    #pragma unroll
    for (int off = 32; off > 0; off >>= 1) ss += __shfl_xor(ss, off, 64);
    float hn = p / fmaxf(sqrtf(ss), 1e-12f);
    hl[lane] = hn;
    __syncthreads();
    float acc = b1[lane];
    #pragma unroll
    for (int j = 0; j < 64; ++j) acc = fmaf(hl[j], w1[j * 64 + lane], acc);
    acc = (acc >= 0.f) ? acc : 0.01f * acc;   // leaky
    float r = acc * w2[lane];
    #pragma unroll
    for (int off = 32; off > 0; off >>= 1) r += __shfl_xor(r, off, 64);
    if (lane == 0) out[g] = r + b2[0];
}

// ---------------- launch ----------------

extern "C" void kernel_launch(void* const* d_in, const int* in_sizes, int n_in,
                              void* d_out, int out_size, void* d_ws, size_t ws_size,
                              hipStream_t stream) {
    const float* x     = (const float*)d_in[0];
    const int*   ei    = (const int*)  d_in[1];
    const float* ea    = (const float*)d_in[2];
    const int*   batch = (const int*)  d_in[3];
    const float *wq1=(const float*)d_in[4],  *bq1=(const float*)d_in[5];
    const float *wk1=(const float*)d_in[6],  *bk1=(const float*)d_in[7];
    const float *wv1=(const float*)d_in[8],  *bv1=(const float*)d_in[9];
    const float *we1=(const float*)d_in[10];
    const float *ws1=(const float*)d_in[11], *bs1=(const float*)d_in[12];
    const float *wq2=(const float*)d_in[13], *bq2=(const float*)d_in[14];
    const float *wk2=(const float*)d_in[15], *bk2=(const float*)d_in[16];
    const float *wv2=(const float*)d_in[17], *bv2=(const float*)d_in[18];
    const float *we2=(const float*)d_in[19];
    const float *ws2=(const float*)d_in[20], *bs2=(const float*)d_in[21];
    const float *wf1=(const float*)d_in[22], *bf1=(const float*)d_in[23];
    const float *wf2=(const float*)d_in[24], *bf2=(const float*)d_in[25];

    int N = in_sizes[0] / 64;
    int E = in_sizes[2] / 16;
    int G = out_size - N * 64;

    const int* srcA = ei;        // edge_index[0]
    const int* dstA = ei + E;    // edge_index[1]

    // workspace layout
    char* w = (char*)d_ws;
    float* qb     = (float*)w; w += (size_t)N * 64 * 4;
    float* kb     = (float*)w; w += (size_t)N * 64 * 4;
    float* vb     = (float*)w; w += (size_t)N * 64 * 4;
    float* hb     = (float*)w; w += (size_t)N * 64 * 4;
    float* pooled = (float*)w; w += (size_t)G * 64 * 4;
    int* row_ptr  = (int*)w;   w += (size_t)(N + 1) * 4;
    int* deg      = (int*)w;   w += (size_t)N * 4;
    int* fill     = (int*)w;   w += (size_t)N * 4;
    int* totals   = (int*)w;   w += 256 * 4;
    int* csr_src  = (int*)w;   w += (size_t)E * 4;
    int* csr_eid  = (int*)w;   w += (size_t)E * 4;

    hipMemsetAsync(deg, 0, (size_t)N * 4, stream);
    hipMemsetAsync(fill, 0, (size_t)N * 4, stream);
    hipMemsetAsync(pooled, 0, (size_t)G * 64 * 4, stream);

    const int TB = 256;
    // CSR build
    hist_kernel<<<(E + TB - 1) / TB, TB, 0, stream>>>(dstA, deg, E);
    int nb = (N + 1023) / 1024;
    scan1_kernel<<<nb, 1024, 0, stream>>>(deg, row_ptr, totals, N);
    scan2_kernel<<<1, 64, 0, stream>>>(totals, nb);
    scan3_kernel<<<(N + TB - 1) / TB, TB, 0, stream>>>(row_ptr, totals, N, E);
    scatter_kernel<<<(E + TB - 1) / TB, TB, 0, stream>>>(srcA, dstA, row_ptr, fill,
                                                         csr_src, csr_eid, E);

    float* outp = (float*)d_out;
    float* atom = outp + G;      // atom_embs region of d_out

    dim3 qgrid((N + QK_TN - 1) / QK_TN, 4);
    int aggBlocks = (N * 64 + TB - 1) / TB;

    // layer 1: x -> hb   (skip pre-stored into hb by qkvs, agg adds+leaky in place)
    qkvs_kernel<<<qgrid, 256, 0, stream>>>(x, wq1, bq1, wk1, bk1, wv1, bv1, ws1, bs1,
                                           qb, kb, vb, hb, N);
    agg_kernel<<<aggBlocks, TB, 0, stream>>>(qb, kb, vb, we1, ea, row_ptr, csr_src,
                                             csr_eid, hb, hb, N);

    // layer 2: hb -> atom (d_out)
    qkvs_kernel<<<qgrid, 256, 0, stream>>>(hb, wq2, bq2, wk2, bk2, wv2, bv2, ws2, bs2,
                                           qb, kb, vb, atom, N);
    agg_kernel<<<aggBlocks, TB, 0, stream>>>(qb, kb, vb, we2, ea, row_ptr, csr_src,
                                             csr_eid, atom, atom, N);

    // pool + head
    pool_kernel<<<(N * 64 + TB - 1) / TB, TB, 0, stream>>>(atom, batch, pooled, N);
    head_kernel<<<G, 64, 0, stream>>>(pooled, wf1, bf1, wf2, bf2, outp, G);
}